// Round 17
// baseline (805.675 us; speedup 1.0000x reference)
//
#include <hip/hip_runtime.h>

#define N_NODES 20000
#define N_EDGES 320000
#define EDG_ALL (N_EDGES + N_NODES)
#define F_IN 128
#define HID 512
#define NB 64
#define NCLS 38
#define M_PAD2 20480       // 160 row-blocks of 128 (padded for XCD swizzle)
#define ROW_BLKS 160
#define NBLK_SCAN ((N_NODES + 255) / 256)   // 79
#define BN_ROWS 16
#define BN_GRID ((N_NODES + BN_ROWS - 1) / BN_ROWS)   // 1250
#define NPART 64
#define POOL_SPLIT 4

typedef short bf16x8 __attribute__((ext_vector_type(8)));
typedef float f32x4 __attribute__((ext_vector_type(4)));
typedef _Float16 f16;
typedef _Float16 f16x2 __attribute__((ext_vector_type(2)));
typedef _Float16 f16x8 __attribute__((ext_vector_type(8)));

__device__ inline unsigned short f2bf(float f) {
  union { float f; unsigned u; } v; v.f = f;
  unsigned r = v.u + 0x7FFF + ((v.u >> 16) & 1);
  return (unsigned short)(r >> 16);
}

// split f into hi(bf16) + lo(bf16 of residual)
__device__ inline void split2(float f, unsigned short& h, unsigned short& l) {
  unsigned short hh = f2bf(f);
  union { unsigned u; float f; } vh; vh.u = ((unsigned)hh) << 16;
  h = hh;
  l = f2bf(f - vh.f);
}

__device__ inline void gload16(const void* g, void* l) {
  __builtin_amdgcn_global_load_lds(
      (const __attribute__((address_space(1))) unsigned int*)g,
      (__attribute__((address_space(3))) unsigned int*)l, 16, 0, 0);
}

__device__ inline float lrelu(float v) { return v > 0.f ? v : 0.2f * v; }

// ---------------- graph preprocessing ----------------

__global__ void deg_count(const int* __restrict__ ei, int* __restrict__ deg) {
  int e = blockIdx.x * blockDim.x + threadIdx.x;
  if (e >= EDG_ALL) return;
  int d = (e < N_EDGES) ? ei[N_EDGES + e] : (e - N_EDGES);
  atomicAdd(&deg[d], 1);
}

__global__ void scan_p1(const int* __restrict__ deg, int* __restrict__ bsum) {
  __shared__ int sh[256];
  int b = blockIdx.x, t = threadIdx.x, i = b * 256 + t;
  sh[t] = (i < N_NODES) ? deg[i] : 0;
  __syncthreads();
  for (int o = 128; o > 0; o >>= 1) {
    if (t < o) sh[t] += sh[t + o];
    __syncthreads();
  }
  if (t == 0) bsum[b] = sh[0];
}

__global__ void scan_p2(const int* __restrict__ bsum, int* __restrict__ boff) {
  __shared__ int sh[128];
  int t = threadIdx.x;
  sh[t] = (t < NBLK_SCAN) ? bsum[t] : 0;
  __syncthreads();
  for (int o = 1; o < 128; o <<= 1) {
    int v = (t >= o) ? sh[t - o] : 0;
    __syncthreads();
    sh[t] += v;
    __syncthreads();
  }
  boff[t] = (t == 0) ? 0 : sh[t - 1];
}

__global__ void scan_p3(const int* __restrict__ deg, const int* __restrict__ boff,
                        int* __restrict__ row_ptr) {
  __shared__ int sh[256];
  int b = blockIdx.x, t = threadIdx.x, i = b * 256 + t;
  sh[t] = (i < N_NODES) ? deg[i] : 0;
  __syncthreads();
  for (int o = 1; o < 256; o <<= 1) {
    int v = (t >= o) ? sh[t - o] : 0;
    __syncthreads();
    sh[t] += v;
    __syncthreads();
  }
  if (i < N_NODES) row_ptr[i + 1] = boff[b] + sh[t];
  if (i == 0) row_ptr[0] = 0;
}

__global__ void compute_norm(const int* __restrict__ deg, float* __restrict__ norm) {
  int i = blockIdx.x * blockDim.x + threadIdx.x;
  if (i >= N_NODES) return;
  norm[i] = rsqrtf(fmaxf((float)deg[i], 1.f));
}

__global__ void fill_csr(const int* __restrict__ ei, int* __restrict__ cursor,
                         int* __restrict__ csr_src) {
  int e = blockIdx.x * blockDim.x + threadIdx.x;
  if (e >= EDG_ALL) return;
  int s, d;
  if (e < N_EDGES) { s = ei[e]; d = ei[N_EDGES + e]; }
  else { s = d = e - N_EDGES; }
  int pos = atomicAdd(&cursor[d], 1);
  csr_src[pos] = s;
}

// ---------------- conversions / transposes ----------------

__global__ void conv_split4(const float* __restrict__ in, unsigned short* __restrict__ hi,
                            unsigned short* __restrict__ lo, int n4) {
  int i = blockIdx.x * blockDim.x + threadIdx.x;
  if (i >= n4) return;
  float4 v = ((const float4*)in)[i];
  ushort4 h, l;
  split2(v.x, h.x, l.x); split2(v.y, h.y, l.y);
  split2(v.z, h.z, l.z); split2(v.w, h.w, l.w);
  ((ushort4*)hi)[i] = h;
  ((ushort4*)lo)[i] = l;
}

// W [K][N] fp32 -> WT hi/lo [N][K] bf16   (K, N multiples of 32)
__global__ __launch_bounds__(256) void wtrans_split(const float* __restrict__ W,
                                                    unsigned short* __restrict__ WTh,
                                                    unsigned short* __restrict__ WTl,
                                                    int K, int N) {
  __shared__ float sh[32][33];
  int k0 = blockIdx.y * 32, n0 = blockIdx.x * 32;
  int r = threadIdx.x >> 5, c = threadIdx.x & 31;
#pragma unroll
  for (int i = 0; i < 4; ++i)
    sh[r + 8 * i][c] = W[(size_t)(k0 + r + 8 * i) * N + n0 + c];
  __syncthreads();
#pragma unroll
  for (int i = 0; i < 4; ++i) {
    unsigned short h, l;
    split2(sh[c][r + 8 * i], h, l);
    WTh[(size_t)(n0 + r + 8 * i) * K + k0 + c] = h;
    WTl[(size_t)(n0 + r + 8 * i) * K + k0 + c] = l;
  }
}

// W [K][N] fp32 -> WT [N][K] fp32, bounds-checked
__global__ __launch_bounds__(256) void ftrans(const float* __restrict__ W,
                                              float* __restrict__ WT, int K, int N) {
  __shared__ float sh[32][33];
  int k0 = blockIdx.y * 32, n0 = blockIdx.x * 32;
  int r = threadIdx.x >> 5, c = threadIdx.x & 31;
#pragma unroll
  for (int i = 0; i < 4; ++i) {
    int k = k0 + r + 8 * i, n = n0 + c;
    sh[r + 8 * i][c] = (k < K && n < N) ? W[(size_t)k * N + n] : 0.f;
  }
  __syncthreads();
#pragma unroll
  for (int i = 0; i < 4; ++i) {
    int n = n0 + r + 8 * i, k = k0 + c;
    if (n < N && k < K) WT[(size_t)n * K + k] = sh[c][r + 8 * i];
  }
}

// ---------------- split-bf16 MFMA GEMM, XCD-swizzled, 2-phase double-buffered ----------------
// Prefetch tile kt+1 into buf^1 while computing tile kt from buf (T3 minimum recipe):
// loads fly under the 48-MFMA phase; one barrier per K-step.

template <int K, typename OT>
__global__ __launch_bounds__(256) void mm_split(const unsigned short* __restrict__ Ah,
                                                const unsigned short* __restrict__ Al,
                                                const unsigned short* __restrict__ Bh,
                                                const unsigned short* __restrict__ Bl,
                                                const float* __restrict__ bias,
                                                OT* __restrict__ C) {
  __shared__ unsigned short AsH[2][4096], AsL[2][4096], BsH[2][4096], BsL[2][4096];
  const int t = threadIdx.x;
  const int wid = t >> 6, l = t & 63;
  const int bid = blockIdx.x;
  const int g = bid >> 5, w = bid & 31;
  const int row0 = (g * 8 + (w & 7)) * 128;
  const int col0 = (w >> 3) * 128;
  const int wm = wid >> 1, wn = wid & 1;

  f32x4 acc[4][4];
#pragma unroll
  for (int m = 0; m < 4; ++m)
#pragma unroll
    for (int n = 0; n < 4; ++n)
#pragma unroll
      for (int q = 0; q < 4; ++q) acc[m][n][q] = 0.f;

  const size_t aoff = (size_t)(row0 + wid * 32 + (l >> 2)) * K + (l & 3) * 8;
  const size_t boff = (size_t)(col0 + wid * 32 + (l >> 2)) * K + (l & 3) * 8;
  const unsigned short* gAh0 = Ah + aoff; const unsigned short* gAh1 = gAh0 + (size_t)16 * K;
  const unsigned short* gAl0 = Al + aoff; const unsigned short* gAl1 = gAl0 + (size_t)16 * K;
  const unsigned short* gBh0 = Bh + boff; const unsigned short* gBh1 = gBh0 + (size_t)16 * K;
  const unsigned short* gBl0 = Bl + boff; const unsigned short* gBl1 = gBl0 + (size_t)16 * K;
  const int c0 = (wid * 2 + 0) * 512;
  const int c1 = (wid * 2 + 1) * 512;

  const int lr = l & 15, kq = (l >> 4) * 8;
  const int NT = K / 32;

  // prologue: stage tile 0 into buffer 0
  {
    gload16(gAh0, &AsH[0][c0]);
    gload16(gAh1, &AsH[0][c1]);
    gload16(gAl0, &AsL[0][c0]);
    gload16(gAl1, &AsL[0][c1]);
    gload16(gBh0, &BsH[0][c0]);
    gload16(gBh1, &BsH[0][c1]);
    gload16(gBl0, &BsL[0][c0]);
    gload16(gBl1, &BsL[0][c1]);
  }

  for (int kt = 0; kt < NT; ++kt) {
    const int cur = kt & 1;
    __syncthreads();                       // drains pending loads of buf[cur], syncs
    if (kt + 1 < NT) {                     // prefetch next tile into buf[cur^1]
      const int ko = (kt + 1) * 32;
      const int nxt = cur ^ 1;
      gload16(gAh0 + ko, &AsH[nxt][c0]);
      gload16(gAh1 + ko, &AsH[nxt][c1]);
      gload16(gAl0 + ko, &AsL[nxt][c0]);
      gload16(gAl1 + ko, &AsL[nxt][c1]);
      gload16(gBh0 + ko, &BsH[nxt][c0]);
      gload16(gBh1 + ko, &BsH[nxt][c1]);
      gload16(gBl0 + ko, &BsL[nxt][c0]);
      gload16(gBl1 + ko, &BsL[nxt][c1]);
    }
    bf16x8 ah[4], al[4], bh[4], bl[4];
#pragma unroll
    for (int m = 0; m < 4; ++m) {
      int ro = (wm * 64 + m * 16 + lr) * 32 + kq;
      ah[m] = *(const bf16x8*)&AsH[cur][ro];
      al[m] = *(const bf16x8*)&AsL[cur][ro];
    }
#pragma unroll
    for (int n = 0; n < 4; ++n) {
      int ro = (wn * 64 + n * 16 + lr) * 32 + kq;
      bh[n] = *(const bf16x8*)&BsH[cur][ro];
      bl[n] = *(const bf16x8*)&BsL[cur][ro];
    }
#pragma unroll
    for (int m = 0; m < 4; ++m)
#pragma unroll
      for (int n = 0; n < 4; ++n) {
        acc[m][n] = __builtin_amdgcn_mfma_f32_16x16x32_bf16(ah[m], bh[n], acc[m][n], 0, 0, 0);
        acc[m][n] = __builtin_amdgcn_mfma_f32_16x16x32_bf16(al[m], bh[n], acc[m][n], 0, 0, 0);
        acc[m][n] = __builtin_amdgcn_mfma_f32_16x16x32_bf16(ah[m], bl[n], acc[m][n], 0, 0, 0);
      }
  }

  const int lg = l >> 4;
#pragma unroll
  for (int m = 0; m < 4; ++m) {
    int row = row0 + wm * 64 + m * 16 + lg * 4;
#pragma unroll
    for (int n = 0; n < 4; ++n) {
      int col = col0 + wn * 64 + n * 16 + lr;
      float bv = bias ? bias[col] : 0.f;
#pragma unroll
      for (int j = 0; j < 4; ++j)
        C[(size_t)(row + j) * HID + col] = (OT)(acc[m][n][j] + bv);
    }
  }
}

// ---------------- batchnorm (train-mode, over rows) — fp16 X plane ----------------

__global__ __launch_bounds__(256) void colstats(const f16* __restrict__ X, int n,
                                                float* __restrict__ part) {
  int t = threadIdx.x;
  int r0 = blockIdx.x * BN_ROWS;
  int r1 = min(r0 + BN_ROWS, n);
  float s0 = 0, q0 = 0, s1 = 0, q1 = 0;
  const f16x2* X2 = (const f16x2*)X;
  for (int r = r0; r < r1; ++r) {
    f16x2 v = X2[(size_t)r * 256 + t];
    float a = (float)v.x, b = (float)v.y;
    s0 += a; q0 += a * a;
    s1 += b; q1 += b * b;
  }
  float* pb = part + (size_t)(blockIdx.x & (NPART - 1)) * 1024;
  atomicAdd(&pb[2 * t], s0);
  atomicAdd(&pb[2 * t + 1], s1);
  atomicAdd(&pb[HID + 2 * t], q0);
  atomicAdd(&pb[HID + 2 * t + 1], q1);
}

// stats[j] = sum_k part[k][j]  (j in [0,1024), 64 partials)
__global__ __launch_bounds__(256) void stats_comb(const float* __restrict__ part,
                                                  float* __restrict__ stats) {
  int j = blockIdx.x * 256 + threadIdx.x;
  float s = 0.f;
#pragma unroll 8
  for (int k = 0; k < NPART; ++k) s += part[(size_t)k * 1024 + j];
  stats[j] = s;
}

// act: 1=leaky_relu(0.2), 2=elu ; reads fp16 X, writes bf16 hi/lo planes; fp16 X in place if writeX
__global__ __launch_bounds__(256) void bn_act(f16* __restrict__ X, int n,
                                              const float* __restrict__ stats,
                                              const float* __restrict__ g,
                                              const float* __restrict__ b, int act,
                                              unsigned short* __restrict__ hio,
                                              unsigned short* __restrict__ loo,
                                              int writeX) {
  int t = threadIdx.x;
  int r0 = blockIdx.x * BN_ROWS;
  int r1 = min(r0 + BN_ROWS, n);
  float invn = 1.f / (float)n;
  float mu0 = stats[2 * t] * invn, mu1 = stats[2 * t + 1] * invn;
  float v0 = stats[HID + 2 * t] * invn - mu0 * mu0;
  float v1 = stats[HID + 2 * t + 1] * invn - mu1 * mu1;
  float2 gg = ((const float2*)g)[t];
  float2 bb = ((const float2*)b)[t];
  float sc0 = gg.x * rsqrtf(v0 + 1e-5f);
  float sc1 = gg.y * rsqrtf(v1 + 1e-5f);
  f16x2* X2 = (f16x2*)X;
  ushort2* H2 = (ushort2*)hio;
  ushort2* L2p = (ushort2*)loo;
  for (int r = r0; r < r1; ++r) {
    f16x2 xv = X2[(size_t)r * 256 + t];
    float y0 = sc0 * ((float)xv.x - mu0) + bb.x;
    float y1 = sc1 * ((float)xv.y - mu1) + bb.y;
    if (act == 1) {
      y0 = y0 > 0.f ? y0 : 0.2f * y0;
      y1 = y1 > 0.f ? y1 : 0.2f * y1;
    } else {
      y0 = y0 > 0.f ? y0 : expm1f(y0);
      y1 = y1 > 0.f ? y1 : expm1f(y1);
    }
    unsigned short h0, l0, h1, l1;
    split2(y0, h0, l0);
    split2(y1, h1, l1);
    ushort2 hh; hh.x = h0; hh.y = h1;
    ushort2 ll; ll.x = l0; ll.y = l1;
    H2[(size_t)r * 256 + t] = hh;
    L2p[(size_t)r * 256 + t] = ll;
    if (writeX) {
      f16x2 yv; yv.x = (f16)y0; yv.y = (f16)y1;
      X2[(size_t)r * 256 + t] = yv;
    }
  }
}

// ---------------- GCN aggregation (wave-per-node, f16x8 in/out) ----------------

__global__ __launch_bounds__(256) void gcn_agg_w(
    const f16* __restrict__ h, const int* __restrict__ row_ptr,
    const int* __restrict__ csr_src, const float* __restrict__ norm,
    const float* __restrict__ bias, f16* __restrict__ out) {
  int node = blockIdx.x * 4 + (threadIdx.x >> 6);
  int l = threadIdx.x & 63;
  int beg = row_ptr[node], end = row_ptr[node + 1];
  float ni = norm[node];
  const f16x8* h8 = (const f16x8*)h;
  float acc[8] = {};
  int e = beg;
  for (; e + 4 <= end; e += 4) {
    int s0 = csr_src[e], s1 = csr_src[e + 1], s2 = csr_src[e + 2], s3 = csr_src[e + 3];
    float c0 = norm[s0] * ni, c1 = norm[s1] * ni, c2 = norm[s2] * ni, c3 = norm[s3] * ni;
    f16x8 v0 = h8[(size_t)s0 * 64 + l];
    f16x8 v1 = h8[(size_t)s1 * 64 + l];
    f16x8 v2 = h8[(size_t)s2 * 64 + l];
    f16x8 v3 = h8[(size_t)s3 * 64 + l];
#pragma unroll
    for (int k = 0; k < 8; ++k)
      acc[k] += c0 * (float)v0[k] + c1 * (float)v1[k] + c2 * (float)v2[k] + c3 * (float)v3[k];
  }
  for (; e < end; ++e) {
    int s = csr_src[e];
    float c = norm[s] * ni;
    f16x8 v = h8[(size_t)s * 64 + l];
#pragma unroll
    for (int k = 0; k < 8; ++k) acc[k] += c * (float)v[k];
  }
  float4 b0 = ((const float4*)bias)[l * 2];
  float4 b1 = ((const float4*)bias)[l * 2 + 1];
  f16x8 o;
  o[0] = (f16)(acc[0] + b0.x); o[1] = (f16)(acc[1] + b0.y);
  o[2] = (f16)(acc[2] + b0.z); o[3] = (f16)(acc[3] + b0.w);
  o[4] = (f16)(acc[4] + b1.x); o[5] = (f16)(acc[5] + b1.y);
  o[6] = (f16)(acc[6] + b1.z); o[7] = (f16)(acc[7] + b1.w);
  ((f16x8*)out)[(size_t)node * 64 + l] = o;
}

// ---------------- GAT ----------------

__device__ inline float wave_sum(float v) {
#pragma unroll
  for (int o = 32; o > 0; o >>= 1) v += __shfl_down(v, o);
  return v;
}

// asn/adn from fp16 h: block per node
__global__ __launch_bounds__(256) void gat_prep_h(
    const f16* __restrict__ h, const float* __restrict__ a_src,
    const float* __restrict__ a_dst, float* __restrict__ asn, float* __restrict__ adn) {
  int i = blockIdx.x;
  int t = threadIdx.x;
  f16x2 hv = ((const f16x2*)h)[(size_t)i * 256 + t];
  float2 as2 = ((const float2*)a_src)[t];
  float2 ad2 = ((const float2*)a_dst)[t];
  float h0 = (float)hv.x, h1 = (float)hv.y;
  float s = h0 * as2.x + h1 * as2.y;
  float d = h0 * ad2.x + h1 * ad2.y;
  s = wave_sum(s); d = wave_sum(d);
  __shared__ float red[4][2];
  int w = t >> 6;
  if ((t & 63) == 0) { red[w][0] = s; red[w][1] = d; }
  __syncthreads();
  if (t == 0) {
    asn[2 * i]     = red[0][0] + red[1][0];   // head 0 = waves 0,1 (threads 0-127)
    asn[2 * i + 1] = red[2][0] + red[3][0];   // head 1 = waves 2,3
    adn[2 * i]     = red[0][1] + red[1][1];
    adn[2 * i + 1] = red[2][1] + red[3][1];
  }
}

// wave-per-node GAT aggregation with half-wave head specialization:
// lanes 0-31 handle head 0, lanes 32-63 head 1 — halves expf + asn loads.
__global__ __launch_bounds__(256) void gat_agg_w(
    const f16* __restrict__ h, const int* __restrict__ row_ptr,
    const int* __restrict__ csr_src, const float* __restrict__ asn,
    const float* __restrict__ adn, const float* __restrict__ bias,
    f16* __restrict__ out) {
  int node = blockIdx.x * 4 + (threadIdx.x >> 6);
  int l = threadIdx.x & 63;
  int hl = l & 31;                 // lane within half-wave
  int hd = (l >> 5) & 1;           // head id: 0 for lanes 0-31, 1 for lanes 32-63
  int beg = row_ptr[node], end = row_ptr[node + 1];
  float aD = adn[2 * node + hd];

  // pass 1: each half-wave covers ALL edges (stride 32) for its own head
  float m = -3.4e38f;
  for (int e = beg + hl; e < end; e += 32) {
    int s = csr_src[e];
    m = fmaxf(m, lrelu(asn[2 * s + hd] + aD));
  }
#pragma unroll
  for (int o = 16; o > 0; o >>= 1) m = fmaxf(m, __shfl_xor(m, o));
  float M = m;                     // uniform within half-wave

  // pass 2: serial edge walk — own-head weight only; sw accumulated in edge order
  const f16x8* h8 = (const f16x8*)h;
  float acc[8] = {};
  float sw = 0.f;
  int e = beg;
  for (; e + 4 <= end; e += 4) {
    int s0 = csr_src[e], s1 = csr_src[e + 1], s2 = csr_src[e + 2], s3 = csr_src[e + 3];
    float u0 = expf(lrelu(asn[2 * s0 + hd] + aD) - M);
    float u1 = expf(lrelu(asn[2 * s1 + hd] + aD) - M);
    float u2 = expf(lrelu(asn[2 * s2 + hd] + aD) - M);
    float u3 = expf(lrelu(asn[2 * s3 + hd] + aD) - M);
    sw += u0 + u1 + u2 + u3;
    f16x8 v0 = h8[(size_t)s0 * 64 + l];
    f16x8 v1 = h8[(size_t)s1 * 64 + l];
    f16x8 v2 = h8[(size_t)s2 * 64 + l];
    f16x8 v3 = h8[(size_t)s3 * 64 + l];
#pragma unroll
    for (int k = 0; k < 8; ++k)
      acc[k] += u0 * (float)v0[k] + u1 * (float)v1[k] + u2 * (float)v2[k] + u3 * (float)v3[k];
  }
  for (; e < end; ++e) {
    int s = csr_src[e];
    float u = expf(lrelu(asn[2 * s + hd] + aD) - M);
    sw += u;
    f16x8 v = h8[(size_t)s * 64 + l];
#pragma unroll
    for (int k = 0; k < 8; ++k) acc[k] += u * (float)v[k];
  }
  float iS = 1.f / sw;
  float4 b0 = ((const float4*)bias)[l * 2];
  float4 b1 = ((const float4*)bias)[l * 2 + 1];
  f16x8 o;
  o[0] = (f16)(acc[0] * iS + b0.x); o[1] = (f16)(acc[1] * iS + b0.y);
  o[2] = (f16)(acc[2] * iS + b0.z); o[3] = (f16)(acc[3] * iS + b0.w);
  o[4] = (f16)(acc[4] * iS + b1.x); o[5] = (f16)(acc[5] * iS + b1.y);
  o[6] = (f16)(acc[6] * iS + b1.z); o[7] = (f16)(acc[7] * iS + b1.w);
  ((f16x8*)out)[(size_t)node * 64 + l] = o;
}

// ---------------- pooling (fp16 input, f16x2-vectorized) ----------------

__global__ void graph_starts(const int* __restrict__ batch, int* __restrict__ start) {
  int i = blockIdx.x * blockDim.x + threadIdx.x;
  if (i >= N_NODES) return;
  int b = batch[i];
  int bp = (i == 0) ? -1 : batch[i - 1];
  for (int g = bp + 1; g <= b; ++g) start[g] = i;
  if (i == N_NODES - 1) {
    for (int g = b + 1; g <= NB; ++g) start[g] = N_NODES;
  }
}

// partial pool: grid (NB, POOL_SPLIT); thread t covers features 2t,2t+1
__global__ __launch_bounds__(256) void pool_part(const f16* __restrict__ h,
                                                 const int* __restrict__ start,
                                                 float* __restrict__ pp_sum,
                                                 float* __restrict__ pp_max) {
  int b = blockIdx.x, ch = blockIdx.y, t = threadIdx.x;
  int s = start[b], e = start[b + 1];
  int len = e - s;
  int c0 = s + (len * ch) / POOL_SPLIT;
  int c1 = s + (len * (ch + 1)) / POOL_SPLIT;
  const f16x2* h2 = (const f16x2*)h;
  float s0 = 0.f, s1 = 0.f, m0 = -3.4e38f, m1 = -3.4e38f;
  int r = c0;
  for (; r + 2 <= c1; r += 2) {
    f16x2 v0 = h2[(size_t)(r + 0) * 256 + t];
    f16x2 v1 = h2[(size_t)(r + 1) * 256 + t];
    float a0 = (float)v0.x, a1 = (float)v0.y, b0 = (float)v1.x, b1 = (float)v1.y;
    s0 += a0 + b0; s1 += a1 + b1;
    m0 = fmaxf(m0, fmaxf(a0, b0));
    m1 = fmaxf(m1, fmaxf(a1, b1));
  }
  for (; r < c1; ++r) {
    f16x2 v = h2[(size_t)r * 256 + t];
    float a0 = (float)v.x, a1 = (float)v.y;
    s0 += a0; s1 += a1;
    m0 = fmaxf(m0, a0); m1 = fmaxf(m1, a1);
  }
  size_t base = ((size_t)b * POOL_SPLIT + ch) * HID;
  pp_sum[base + 2 * t] = s0;
  pp_sum[base + 2 * t + 1] = s1;
  pp_max[base + 2 * t] = m0;
  pp_max[base + 2 * t + 1] = m1;
}

__global__ __launch_bounds__(512) void pool_comb(const float* __restrict__ pp_sum,
                                                 const float* __restrict__ pp_max,
                                                 const int* __restrict__ start,
                                                 float* __restrict__ p) {
  int b = blockIdx.x, t = threadIdx.x;
  float sum = 0.f, mx = -3.4e38f;
#pragma unroll
  for (int ch = 0; ch < POOL_SPLIT; ++ch) {
    sum += pp_sum[((size_t)b * POOL_SPLIT + ch) * HID + t];
    mx = fmaxf(mx, pp_max[((size_t)b * POOL_SPLIT + ch) * HID + t]);
  }
  float cnt = (float)(start[b + 1] - start[b]);
  p[b * 1024 + t] = sum / fmaxf(cnt, 1.f);
  p[b * 1024 + 512 + t] = mx;
}

// ---------------- classifier ----------------

__global__ __launch_bounds__(256) void fc_wave(const float* __restrict__ A,
                                               const float* __restrict__ WT,
                                               const float* __restrict__ bias,
                                               float* __restrict__ C, int K, int Ncol) {
  int r = blockIdx.x;
  int wid = threadIdx.x >> 6, l = threadIdx.x & 63;
  int c = blockIdx.y * 4 + wid;
  if (c >= Ncol) return;
  const float* a = A + (size_t)r * K;
  const float* w = WT + (size_t)c * K;
  float s = 0.f;
  for (int k = l; k < K; k += 64) s += a[k] * w[k];
#pragma unroll
  for (int o = 32; o > 0; o >>= 1) s += __shfl_down(s, o);
  if (l == 0) C[(size_t)r * Ncol + c] = s + bias[c];
}

__global__ void bn_small(float* __restrict__ X, int R, int C,
                         const float* __restrict__ g, const float* __restrict__ b, int act) {
  int c = blockIdx.x * blockDim.x + threadIdx.x;
  if (c >= C) return;
  float s = 0.f, q = 0.f;
  for (int r = 0; r < R; ++r) {
    float v = X[r * C + c];
    s += v; q += v * v;
  }
  float mu = s / R;
  float var = q / R - mu * mu;
  float sc = g[c] * rsqrtf(var + 1e-5f);
  float bb = b[c];
  for (int r = 0; r < R; ++r) {
    float v = sc * (X[r * C + c] - mu) + bb;
    if (act == 1) v = v > 0.f ? v : 0.2f * v;
    X[r * C + c] = v;
  }
}

// ---------------- launch ----------------

extern "C" void kernel_launch(void* const* d_in, const int* in_sizes, int n_in,
                              void* d_out, int out_size, void* d_ws, size_t ws_size,
                              hipStream_t stream) {
  const float* x      = (const float*)d_in[0];
  const int*   ei     = (const int*)d_in[1];
  const int*   batch  = (const int*)d_in[2];
  const float* ft_W   = (const float*)d_in[3];
  const float* ft_b   = (const float*)d_in[4];
  const float* ft_g   = (const float*)d_in[5];
  const float* ft_be  = (const float*)d_in[6];
  const float* gcn1_W = (const float*)d_in[7];
  const float* gcn1_b = (const float*)d_in[8];
  const float* gbn1_g = (const float*)d_in[9];
  const float* gbn1_b = (const float*)d_in[10];
  const float* gcn2_W = (const float*)d_in[11];
  const float* gcn2_b = (const float*)d_in[12];
  const float* gbn2_g = (const float*)d_in[13];
  const float* gbn2_b = (const float*)d_in[14];
  const float* gat1_W = (const float*)d_in[15];
  const float* gat1_as= (const float*)d_in[16];
  const float* gat1_ad= (const float*)d_in[17];
  const float* gat1_b = (const float*)d_in[18];
  const float* abn1_g = (const float*)d_in[19];
  const float* abn1_b = (const float*)d_in[20];
  const float* gat2_W = (const float*)d_in[21];
  const float* gat2_as= (const float*)d_in[22];
  const float* gat2_ad= (const float*)d_in[23];
  const float* gat2_b = (const float*)d_in[24];
  const float* abn2_g = (const float*)d_in[25];
  const float* abn2_b = (const float*)d_in[26];
  const float* fc1_W  = (const float*)d_in[27];
  const float* fc1_b  = (const float*)d_in[28];
  const float* cbn1_g = (const float*)d_in[29];
  const float* cbn1_b = (const float*)d_in[30];
  const float* fc2_W  = (const float*)d_in[31];
  const float* fc2_b  = (const float*)d_in[32];
  const float* cbn2_g = (const float*)d_in[33];
  const float* cbn2_b = (const float*)d_in[34];
  const float* out_W  = (const float*)d_in[35];
  const float* out_b  = (const float*)d_in[36];

  char* ws = (char*)d_ws;
  size_t off = 0;
  auto alloc = [&](size_t bytes) -> void* {
    void* p = ws + off;
    off = (off + bytes + 255) & ~(size_t)255;
    return p;
  };

  float* buf0 = (float*)alloc((size_t)M_PAD2 * HID * 4);       // fp16 X plane (aliases xhi/xlo early)
  float* buf1 = (float*)alloc((size_t)M_PAD2 * HID * 4);       // fp16 GEMM out
  unsigned short* ahi = (unsigned short*)alloc((size_t)M_PAD2 * HID * 2);
  unsigned short* alo = (unsigned short*)alloc((size_t)M_PAD2 * HID * 2);
  unsigned short* wh_ft = (unsigned short*)alloc((size_t)HID * F_IN * 2);
  unsigned short* wl_ft = (unsigned short*)alloc((size_t)HID * F_IN * 2);
  unsigned short* wh_g1 = (unsigned short*)alloc((size_t)HID * HID * 2);
  unsigned short* wl_g1 = (unsigned short*)alloc((size_t)HID * HID * 2);
  unsigned short* wh_g2 = (unsigned short*)alloc((size_t)HID * HID * 2);
  unsigned short* wl_g2 = (unsigned short*)alloc((size_t)HID * HID * 2);
  unsigned short* wh_a1 = (unsigned short*)alloc((size_t)HID * HID * 2);
  unsigned short* wl_a1 = (unsigned short*)alloc((size_t)HID * HID * 2);
  unsigned short* wh_a2 = (unsigned short*)alloc((size_t)HID * HID * 2);
  unsigned short* wl_a2 = (unsigned short*)alloc((size_t)HID * HID * 2);
  float* fc1t = (float*)alloc((size_t)512 * 1024 * 4);
  float* fc2t = (float*)alloc((size_t)256 * 512 * 4);
  float* outt = (float*)alloc((size_t)NCLS * 256 * 4);
  int*   row_ptr = (int*)alloc((N_NODES + 1) * 4);
  int*   cursor  = (int*)alloc(N_NODES * 4);
  int*   deg     = (int*)alloc(N_NODES * 4);
  int*   csr_src = (int*)alloc(EDG_ALL * 4);
  float* norm    = (float*)alloc(N_NODES * 4);
  float* asn     = (float*)alloc(N_NODES * 2 * 4);
  float* adn     = (float*)alloc(N_NODES * 2 * 4);
  float* stats   = (float*)alloc(1024 * 4);
  float* spart   = (float*)alloc((size_t)NPART * 1024 * 4);
  int*   bsum    = (int*)alloc(128 * 4);
  int*   boff    = (int*)alloc(128 * 4);
  int*   start   = (int*)alloc((NB + 1) * 4);
  float* p       = (float*)alloc(NB * 1024 * 4);
  float* pp_sum  = (float*)alloc((size_t)NB * POOL_SPLIT * HID * 4);
  float* pp_max  = (float*)alloc((size_t)NB * POOL_SPLIT * HID * 4);
  float* z1      = (float*)alloc(NB * HID * 4);
  float* z2      = (float*)alloc(NB * 256 * 4);
  // x hi/lo alias buf0 (dead before buf0 first written by gcn_agg)
  unsigned short* xhi = (unsigned short*)buf0;
  unsigned short* xlo = xhi + (size_t)M_PAD2 * F_IN;
  f16* xbuf = (f16*)buf0;   // fp16 X plane (agg outputs)
  f16* hbuf = (f16*)buf1;   // fp16 GEMM output view

  const dim3 blk256(256);
  const dim3 mmGrid(ROW_BLKS * 4);   // linear grid, XCD-swizzled inside kernel
  const int aggGrid = N_NODES / 4;   // wave-per-node, 4 nodes/block

  // BN macro: NPART-atomic colstats + combine + bn_act (all fp16 X)
#define BN_BLOCK(XBUF, G, B, ACT, WX)                                            \
  hipMemsetAsync(spart, 0, (size_t)NPART * 1024 * 4, stream);                    \
  colstats<<<BN_GRID, blk256, 0, stream>>>(XBUF, N_NODES, spart);                \
  stats_comb<<<4, blk256, 0, stream>>>(spart, stats);                            \
  bn_act<<<BN_GRID, blk256, 0, stream>>>(XBUF, N_NODES, stats, G, B, ACT, ahi, alo, WX);

  // --- graph preprocessing ---
  hipMemsetAsync(deg, 0, N_NODES * 4, stream);
  deg_count<<<(EDG_ALL + 255) / 256, blk256, 0, stream>>>(ei, deg);
  scan_p1<<<NBLK_SCAN, blk256, 0, stream>>>(deg, bsum);
  scan_p2<<<1, 128, 0, stream>>>(bsum, boff);
  scan_p3<<<NBLK_SCAN, blk256, 0, stream>>>(deg, boff, row_ptr);
  compute_norm<<<(N_NODES + 255) / 256, blk256, 0, stream>>>(deg, norm);
  hipMemcpyAsync(cursor, row_ptr, N_NODES * 4, hipMemcpyDeviceToDevice, stream);
  fill_csr<<<(EDG_ALL + 255) / 256, blk256, 0, stream>>>(ei, cursor, csr_src);

  // --- weight prep (split bf16, transposed) ---
  wtrans_split<<<dim3(HID / 32, F_IN / 32), blk256, 0, stream>>>(ft_W, wh_ft, wl_ft, F_IN, HID);
  wtrans_split<<<dim3(HID / 32, HID / 32), blk256, 0, stream>>>(gcn1_W, wh_g1, wl_g1, HID, HID);
  wtrans_split<<<dim3(HID / 32, HID / 32), blk256, 0, stream>>>(gcn2_W, wh_g2, wl_g2, HID, HID);
  wtrans_split<<<dim3(HID / 32, HID / 32), blk256, 0, stream>>>(gat1_W, wh_a1, wl_a1, HID, HID);
  wtrans_split<<<dim3(HID / 32, HID / 32), blk256, 0, stream>>>(gat2_W, wh_a2, wl_a2, HID, HID);
  ftrans<<<dim3(512 / 32, 1024 / 32), blk256, 0, stream>>>(fc1_W, fc1t, 1024, 512);
  ftrans<<<dim3(256 / 32, 512 / 32), blk256, 0, stream>>>(fc2_W, fc2t, 512, 256);
  ftrans<<<dim3((NCLS + 31) / 32, 256 / 32), blk256, 0, stream>>>(out_W, outt, 256, NCLS);

  // --- feature transform: Linear(split MFMA, fp16 out) -> BN -> LeakyReLU ---
  conv_split4<<<(N_NODES * F_IN / 4 + 255) / 256, blk256, 0, stream>>>(x, xhi, xlo, N_NODES * F_IN / 4);
  mm_split<F_IN, f16><<<mmGrid, blk256, 0, stream>>>(xhi, xlo, wh_ft, wl_ft, ft_b, hbuf);
  BN_BLOCK(hbuf, ft_g, ft_be, 1, 0)

  // --- GCN1 ---
  mm_split<HID, f16><<<mmGrid, blk256, 0, stream>>>(ahi, alo, wh_g1, wl_g1, nullptr, hbuf);
  gcn_agg_w<<<aggGrid, blk256, 0, stream>>>(hbuf, row_ptr, csr_src, norm, gcn1_b, xbuf);
  BN_BLOCK(xbuf, gbn1_g, gbn1_b, 2, 0)

  // --- GCN2 ---
  mm_split<HID, f16><<<mmGrid, blk256, 0, stream>>>(ahi, alo, wh_g2, wl_g2, nullptr, hbuf);
  gcn_agg_w<<<aggGrid, blk256, 0, stream>>>(hbuf, row_ptr, csr_src, norm, gcn2_b, xbuf);
  BN_BLOCK(xbuf, gbn2_g, gbn2_b, 2, 0)

  // --- GAT1 ---
  mm_split<HID, f16><<<mmGrid, blk256, 0, stream>>>(ahi, alo, wh_a1, wl_a1, nullptr, hbuf);
  gat_prep_h<<<N_NODES, blk256, 0, stream>>>(hbuf, gat1_as, gat1_ad, asn, adn);
  gat_agg_w<<<aggGrid, blk256, 0, stream>>>(hbuf, row_ptr, csr_src, asn, adn, gat1_b, xbuf);
  BN_BLOCK(xbuf, abn1_g, abn1_b, 2, 0)

  // --- GAT2 ---
  mm_split<HID, f16><<<mmGrid, blk256, 0, stream>>>(ahi, alo, wh_a2, wl_a2, nullptr, hbuf);
  gat_prep_h<<<N_NODES, blk256, 0, stream>>>(hbuf, gat2_as, gat2_ad, asn, adn);
  gat_agg_w<<<aggGrid, blk256, 0, stream>>>(hbuf, row_ptr, csr_src, asn, adn, gat2_b, xbuf);
  BN_BLOCK(xbuf, abn2_g, abn2_b, 2, 1)

  // --- pooling (reads fp16 X) ---
  graph_starts<<<(N_NODES + 255) / 256, blk256, 0, stream>>>(batch, start);
  pool_part<<<dim3(NB, POOL_SPLIT), blk256, 0, stream>>>(xbuf, start, pp_sum, pp_max);
  pool_comb<<<NB, dim3(512), 0, stream>>>(pp_sum, pp_max, start, p);

  // --- classifier ---
  fc_wave<<<dim3(NB, 128), blk256, 0, stream>>>(p, fc1t, fc1_b, z1, 1024, 512);
  bn_small<<<2, blk256, 0, stream>>>(z1, NB, 512, cbn1_g, cbn1_b, 0);
  fc_wave<<<dim3(NB, 64), blk256, 0, stream>>>(z1, fc2t, fc2_b, z2, 512, 256);
  bn_small<<<1, blk256, 0, stream>>>(z2, NB, 256, cbn2_g, cbn2_b, 1);
  fc_wave<<<dim3(NB, 10), blk256, 0, stream>>>(z2, outt, out_b, (float*)d_out, 256, NCLS);

#undef BN_BLOCK
  (void)in_sizes; (void)n_in; (void)out_size; (void)ws_size;
}

// Round 18
// 776.451 us; speedup vs baseline: 1.0376x; 1.0376x over previous
//
#include <hip/hip_runtime.h>

#define N_NODES 20000
#define N_EDGES 320000
#define EDG_ALL (N_EDGES + N_NODES)
#define F_IN 128
#define HID 512
#define NB 64
#define NCLS 38
#define M_PAD2 20480       // 160 row-blocks of 128 (padded for XCD swizzle)
#define ROW_BLKS 160
#define NBLK_SCAN ((N_NODES + 255) / 256)   // 79
#define BN_ROWS 16
#define BN_GRID ((N_NODES + BN_ROWS - 1) / BN_ROWS)   // 1250
#define NPART 64
#define POOL_SPLIT 4

typedef short bf16x8 __attribute__((ext_vector_type(8)));
typedef float f32x4 __attribute__((ext_vector_type(4)));
typedef _Float16 f16;
typedef _Float16 f16x2 __attribute__((ext_vector_type(2)));
typedef _Float16 f16x8 __attribute__((ext_vector_type(8)));

__device__ inline unsigned short f2bf(float f) {
  union { float f; unsigned u; } v; v.f = f;
  unsigned r = v.u + 0x7FFF + ((v.u >> 16) & 1);
  return (unsigned short)(r >> 16);
}

// split f into hi(bf16) + lo(bf16 of residual)
__device__ inline void split2(float f, unsigned short& h, unsigned short& l) {
  unsigned short hh = f2bf(f);
  union { unsigned u; float f; } vh; vh.u = ((unsigned)hh) << 16;
  h = hh;
  l = f2bf(f - vh.f);
}

__device__ inline void gload16(const void* g, void* l) {
  __builtin_amdgcn_global_load_lds(
      (const __attribute__((address_space(1))) unsigned int*)g,
      (__attribute__((address_space(3))) unsigned int*)l, 16, 0, 0);
}

__device__ inline float lrelu(float v) { return v > 0.f ? v : 0.2f * v; }

// ---------------- graph preprocessing ----------------

__global__ void deg_count(const int* __restrict__ ei, int* __restrict__ deg) {
  int e = blockIdx.x * blockDim.x + threadIdx.x;
  if (e >= EDG_ALL) return;
  int d = (e < N_EDGES) ? ei[N_EDGES + e] : (e - N_EDGES);
  atomicAdd(&deg[d], 1);
}

__global__ void scan_p1(const int* __restrict__ deg, int* __restrict__ bsum) {
  __shared__ int sh[256];
  int b = blockIdx.x, t = threadIdx.x, i = b * 256 + t;
  sh[t] = (i < N_NODES) ? deg[i] : 0;
  __syncthreads();
  for (int o = 128; o > 0; o >>= 1) {
    if (t < o) sh[t] += sh[t + o];
    __syncthreads();
  }
  if (t == 0) bsum[b] = sh[0];
}

__global__ void scan_p2(const int* __restrict__ bsum, int* __restrict__ boff) {
  __shared__ int sh[128];
  int t = threadIdx.x;
  sh[t] = (t < NBLK_SCAN) ? bsum[t] : 0;
  __syncthreads();
  for (int o = 1; o < 128; o <<= 1) {
    int v = (t >= o) ? sh[t - o] : 0;
    __syncthreads();
    sh[t] += v;
    __syncthreads();
  }
  boff[t] = (t == 0) ? 0 : sh[t - 1];
}

__global__ void scan_p3(const int* __restrict__ deg, const int* __restrict__ boff,
                        int* __restrict__ row_ptr) {
  __shared__ int sh[256];
  int b = blockIdx.x, t = threadIdx.x, i = b * 256 + t;
  sh[t] = (i < N_NODES) ? deg[i] : 0;
  __syncthreads();
  for (int o = 1; o < 256; o <<= 1) {
    int v = (t >= o) ? sh[t - o] : 0;
    __syncthreads();
    sh[t] += v;
    __syncthreads();
  }
  if (i < N_NODES) row_ptr[i + 1] = boff[b] + sh[t];
  if (i == 0) row_ptr[0] = 0;
}

__global__ void compute_norm(const int* __restrict__ deg, float* __restrict__ norm) {
  int i = blockIdx.x * blockDim.x + threadIdx.x;
  if (i >= N_NODES) return;
  norm[i] = rsqrtf(fmaxf((float)deg[i], 1.f));
}

__global__ void fill_csr(const int* __restrict__ ei, int* __restrict__ cursor,
                         int* __restrict__ csr_src) {
  int e = blockIdx.x * blockDim.x + threadIdx.x;
  if (e >= EDG_ALL) return;
  int s, d;
  if (e < N_EDGES) { s = ei[e]; d = ei[N_EDGES + e]; }
  else { s = d = e - N_EDGES; }
  int pos = atomicAdd(&cursor[d], 1);
  csr_src[pos] = s;
}

// ---------------- conversions / transposes ----------------

__global__ void conv_split4(const float* __restrict__ in, unsigned short* __restrict__ hi,
                            unsigned short* __restrict__ lo, int n4) {
  int i = blockIdx.x * blockDim.x + threadIdx.x;
  if (i >= n4) return;
  float4 v = ((const float4*)in)[i];
  ushort4 h, l;
  split2(v.x, h.x, l.x); split2(v.y, h.y, l.y);
  split2(v.z, h.z, l.z); split2(v.w, h.w, l.w);
  ((ushort4*)hi)[i] = h;
  ((ushort4*)lo)[i] = l;
}

// W [K][N] fp32 -> WT hi/lo [N][K] bf16   (K, N multiples of 32)
__global__ __launch_bounds__(256) void wtrans_split(const float* __restrict__ W,
                                                    unsigned short* __restrict__ WTh,
                                                    unsigned short* __restrict__ WTl,
                                                    int K, int N) {
  __shared__ float sh[32][33];
  int k0 = blockIdx.y * 32, n0 = blockIdx.x * 32;
  int r = threadIdx.x >> 5, c = threadIdx.x & 31;
#pragma unroll
  for (int i = 0; i < 4; ++i)
    sh[r + 8 * i][c] = W[(size_t)(k0 + r + 8 * i) * N + n0 + c];
  __syncthreads();
#pragma unroll
  for (int i = 0; i < 4; ++i) {
    unsigned short h, l;
    split2(sh[c][r + 8 * i], h, l);
    WTh[(size_t)(n0 + r + 8 * i) * K + k0 + c] = h;
    WTl[(size_t)(n0 + r + 8 * i) * K + k0 + c] = l;
  }
}

// W [K][N] fp32 -> WT [N][K] fp32, bounds-checked
__global__ __launch_bounds__(256) void ftrans(const float* __restrict__ W,
                                              float* __restrict__ WT, int K, int N) {
  __shared__ float sh[32][33];
  int k0 = blockIdx.y * 32, n0 = blockIdx.x * 32;
  int r = threadIdx.x >> 5, c = threadIdx.x & 31;
#pragma unroll
  for (int i = 0; i < 4; ++i) {
    int k = k0 + r + 8 * i, n = n0 + c;
    sh[r + 8 * i][c] = (k < K && n < N) ? W[(size_t)k * N + n] : 0.f;
  }
  __syncthreads();
#pragma unroll
  for (int i = 0; i < 4; ++i) {
    int n = n0 + r + 8 * i, k = k0 + c;
    if (n < N && k < K) WT[(size_t)n * K + k] = sh[c][r + 8 * i];
  }
}

// ---------------- split-bf16 MFMA GEMM, XCD-swizzled, single-buffer (R16 proven) ----------------

template <int K, typename OT>
__global__ __launch_bounds__(256) void mm_split(const unsigned short* __restrict__ Ah,
                                                const unsigned short* __restrict__ Al,
                                                const unsigned short* __restrict__ Bh,
                                                const unsigned short* __restrict__ Bl,
                                                const float* __restrict__ bias,
                                                OT* __restrict__ C) {
  __shared__ unsigned short AsH[4096], AsL[4096], BsH[4096], BsL[4096];
  const int t = threadIdx.x;
  const int wid = t >> 6, l = t & 63;
  const int bid = blockIdx.x;
  const int g = bid >> 5, w = bid & 31;
  const int row0 = (g * 8 + (w & 7)) * 128;
  const int col0 = (w >> 3) * 128;
  const int wm = wid >> 1, wn = wid & 1;

  f32x4 acc[4][4];
#pragma unroll
  for (int m = 0; m < 4; ++m)
#pragma unroll
    for (int n = 0; n < 4; ++n)
#pragma unroll
      for (int q = 0; q < 4; ++q) acc[m][n][q] = 0.f;

  const size_t aoff = (size_t)(row0 + wid * 32 + (l >> 2)) * K + (l & 3) * 8;
  const size_t boff = (size_t)(col0 + wid * 32 + (l >> 2)) * K + (l & 3) * 8;
  const unsigned short* gAh0 = Ah + aoff; const unsigned short* gAh1 = gAh0 + (size_t)16 * K;
  const unsigned short* gAl0 = Al + aoff; const unsigned short* gAl1 = gAl0 + (size_t)16 * K;
  const unsigned short* gBh0 = Bh + boff; const unsigned short* gBh1 = gBh0 + (size_t)16 * K;
  const unsigned short* gBl0 = Bl + boff; const unsigned short* gBl1 = gBl0 + (size_t)16 * K;
  unsigned short* lAh0 = &AsH[(wid * 2 + 0) * 512];
  unsigned short* lAh1 = &AsH[(wid * 2 + 1) * 512];
  unsigned short* lAl0 = &AsL[(wid * 2 + 0) * 512];
  unsigned short* lAl1 = &AsL[(wid * 2 + 1) * 512];
  unsigned short* lBh0 = &BsH[(wid * 2 + 0) * 512];
  unsigned short* lBh1 = &BsH[(wid * 2 + 1) * 512];
  unsigned short* lBl0 = &BsL[(wid * 2 + 0) * 512];
  unsigned short* lBl1 = &BsL[(wid * 2 + 1) * 512];

  const int lr = l & 15, kq = (l >> 4) * 8;

  for (int kt = 0; kt < K / 32; ++kt) {
    const int ko = kt * 32;
    gload16(gAh0 + ko, lAh0);
    gload16(gAh1 + ko, lAh1);
    gload16(gAl0 + ko, lAl0);
    gload16(gAl1 + ko, lAl1);
    gload16(gBh0 + ko, lBh0);
    gload16(gBh1 + ko, lBh1);
    gload16(gBl0 + ko, lBl0);
    gload16(gBl1 + ko, lBl1);
    __syncthreads();
    bf16x8 ah[4], al[4], bh[4], bl[4];
#pragma unroll
    for (int m = 0; m < 4; ++m) {
      int ro = (wm * 64 + m * 16 + lr) * 32 + kq;
      ah[m] = *(const bf16x8*)&AsH[ro];
      al[m] = *(const bf16x8*)&AsL[ro];
    }
#pragma unroll
    for (int n = 0; n < 4; ++n) {
      int ro = (wn * 64 + n * 16 + lr) * 32 + kq;
      bh[n] = *(const bf16x8*)&BsH[ro];
      bl[n] = *(const bf16x8*)&BsL[ro];
    }
#pragma unroll
    for (int m = 0; m < 4; ++m)
#pragma unroll
      for (int n = 0; n < 4; ++n) {
        acc[m][n] = __builtin_amdgcn_mfma_f32_16x16x32_bf16(ah[m], bh[n], acc[m][n], 0, 0, 0);
        acc[m][n] = __builtin_amdgcn_mfma_f32_16x16x32_bf16(al[m], bh[n], acc[m][n], 0, 0, 0);
        acc[m][n] = __builtin_amdgcn_mfma_f32_16x16x32_bf16(ah[m], bl[n], acc[m][n], 0, 0, 0);
      }
    __syncthreads();
  }

  const int lg = l >> 4;
#pragma unroll
  for (int m = 0; m < 4; ++m) {
    int row = row0 + wm * 64 + m * 16 + lg * 4;
#pragma unroll
    for (int n = 0; n < 4; ++n) {
      int col = col0 + wn * 64 + n * 16 + lr;
      float bv = bias ? bias[col] : 0.f;
#pragma unroll
      for (int j = 0; j < 4; ++j)
        C[(size_t)(row + j) * HID + col] = (OT)(acc[m][n][j] + bv);
    }
  }
}

// ---------------- batchnorm (train-mode, over rows) — fp16 X plane ----------------

__global__ __launch_bounds__(256) void colstats(const f16* __restrict__ X, int n,
                                                float* __restrict__ part) {
  int t = threadIdx.x;
  int r0 = blockIdx.x * BN_ROWS;
  int r1 = min(r0 + BN_ROWS, n);
  float s0 = 0, q0 = 0, s1 = 0, q1 = 0;
  const f16x2* X2 = (const f16x2*)X;
  for (int r = r0; r < r1; ++r) {
    f16x2 v = X2[(size_t)r * 256 + t];
    float a = (float)v.x, b = (float)v.y;
    s0 += a; q0 += a * a;
    s1 += b; q1 += b * b;
  }
  float* pb = part + (size_t)(blockIdx.x & (NPART - 1)) * 1024;
  atomicAdd(&pb[2 * t], s0);
  atomicAdd(&pb[2 * t + 1], s1);
  atomicAdd(&pb[HID + 2 * t], q0);
  atomicAdd(&pb[HID + 2 * t + 1], q1);
}

// stats[j] = sum_k part[k][j]; also re-zeroes part for the next layer (no race:
// this thread is the only reader/writer of column j).
__global__ __launch_bounds__(256) void stats_comb(float* __restrict__ part,
                                                  float* __restrict__ stats) {
  int j = blockIdx.x * 256 + threadIdx.x;
  float s = 0.f;
#pragma unroll 8
  for (int k = 0; k < NPART; ++k) {
    s += part[(size_t)k * 1024 + j];
    part[(size_t)k * 1024 + j] = 0.f;
  }
  stats[j] = s;
}

// act: 1=leaky_relu(0.2), 2=elu ; reads fp16 X, writes bf16 hi/lo planes; fp16 X in place if writeX
__global__ __launch_bounds__(256) void bn_act(f16* __restrict__ X, int n,
                                              const float* __restrict__ stats,
                                              const float* __restrict__ g,
                                              const float* __restrict__ b, int act,
                                              unsigned short* __restrict__ hio,
                                              unsigned short* __restrict__ loo,
                                              int writeX) {
  int t = threadIdx.x;
  int r0 = blockIdx.x * BN_ROWS;
  int r1 = min(r0 + BN_ROWS, n);
  float invn = 1.f / (float)n;
  float mu0 = stats[2 * t] * invn, mu1 = stats[2 * t + 1] * invn;
  float v0 = stats[HID + 2 * t] * invn - mu0 * mu0;
  float v1 = stats[HID + 2 * t + 1] * invn - mu1 * mu1;
  float2 gg = ((const float2*)g)[t];
  float2 bb = ((const float2*)b)[t];
  float sc0 = gg.x * rsqrtf(v0 + 1e-5f);
  float sc1 = gg.y * rsqrtf(v1 + 1e-5f);
  f16x2* X2 = (f16x2*)X;
  ushort2* H2 = (ushort2*)hio;
  ushort2* L2p = (ushort2*)loo;
  for (int r = r0; r < r1; ++r) {
    f16x2 xv = X2[(size_t)r * 256 + t];
    float y0 = sc0 * ((float)xv.x - mu0) + bb.x;
    float y1 = sc1 * ((float)xv.y - mu1) + bb.y;
    if (act == 1) {
      y0 = y0 > 0.f ? y0 : 0.2f * y0;
      y1 = y1 > 0.f ? y1 : 0.2f * y1;
    } else {
      y0 = y0 > 0.f ? y0 : expm1f(y0);
      y1 = y1 > 0.f ? y1 : expm1f(y1);
    }
    unsigned short h0, l0, h1, l1;
    split2(y0, h0, l0);
    split2(y1, h1, l1);
    ushort2 hh; hh.x = h0; hh.y = h1;
    ushort2 ll; ll.x = l0; ll.y = l1;
    H2[(size_t)r * 256 + t] = hh;
    L2p[(size_t)r * 256 + t] = ll;
    if (writeX) {
      f16x2 yv; yv.x = (f16)y0; yv.y = (f16)y1;
      X2[(size_t)r * 256 + t] = yv;
    }
  }
}

// ---------------- GCN aggregation (wave-per-node, f16x8 in/out) ----------------

__global__ __launch_bounds__(256) void gcn_agg_w(
    const f16* __restrict__ h, const int* __restrict__ row_ptr,
    const int* __restrict__ csr_src, const float* __restrict__ norm,
    const float* __restrict__ bias, f16* __restrict__ out) {
  int node = blockIdx.x * 4 + (threadIdx.x >> 6);
  int l = threadIdx.x & 63;
  int beg = row_ptr[node], end = row_ptr[node + 1];
  float ni = norm[node];
  const f16x8* h8 = (const f16x8*)h;
  float acc[8] = {};
  int e = beg;
  for (; e + 4 <= end; e += 4) {
    int s0 = csr_src[e], s1 = csr_src[e + 1], s2 = csr_src[e + 2], s3 = csr_src[e + 3];
    float c0 = norm[s0] * ni, c1 = norm[s1] * ni, c2 = norm[s2] * ni, c3 = norm[s3] * ni;
    f16x8 v0 = h8[(size_t)s0 * 64 + l];
    f16x8 v1 = h8[(size_t)s1 * 64 + l];
    f16x8 v2 = h8[(size_t)s2 * 64 + l];
    f16x8 v3 = h8[(size_t)s3 * 64 + l];
#pragma unroll
    for (int k = 0; k < 8; ++k)
      acc[k] += c0 * (float)v0[k] + c1 * (float)v1[k] + c2 * (float)v2[k] + c3 * (float)v3[k];
  }
  for (; e < end; ++e) {
    int s = csr_src[e];
    float c = norm[s] * ni;
    f16x8 v = h8[(size_t)s * 64 + l];
#pragma unroll
    for (int k = 0; k < 8; ++k) acc[k] += c * (float)v[k];
  }
  float4 b0 = ((const float4*)bias)[l * 2];
  float4 b1 = ((const float4*)bias)[l * 2 + 1];
  f16x8 o;
  o[0] = (f16)(acc[0] + b0.x); o[1] = (f16)(acc[1] + b0.y);
  o[2] = (f16)(acc[2] + b0.z); o[3] = (f16)(acc[3] + b0.w);
  o[4] = (f16)(acc[4] + b1.x); o[5] = (f16)(acc[5] + b1.y);
  o[6] = (f16)(acc[6] + b1.z); o[7] = (f16)(acc[7] + b1.w);
  ((f16x8*)out)[(size_t)node * 64 + l] = o;
}

// ---------------- GAT ----------------

__device__ inline float wave_sum(float v) {
#pragma unroll
  for (int o = 32; o > 0; o >>= 1) v += __shfl_down(v, o);
  return v;
}

// asn/adn from fp16 h: block per node
__global__ __launch_bounds__(256) void gat_prep_h(
    const f16* __restrict__ h, const float* __restrict__ a_src,
    const float* __restrict__ a_dst, float* __restrict__ asn, float* __restrict__ adn) {
  int i = blockIdx.x;
  int t = threadIdx.x;
  f16x2 hv = ((const f16x2*)h)[(size_t)i * 256 + t];
  float2 as2 = ((const float2*)a_src)[t];
  float2 ad2 = ((const float2*)a_dst)[t];
  float h0 = (float)hv.x, h1 = (float)hv.y;
  float s = h0 * as2.x + h1 * as2.y;
  float d = h0 * ad2.x + h1 * ad2.y;
  s = wave_sum(s); d = wave_sum(d);
  __shared__ float red[4][2];
  int w = t >> 6;
  if ((t & 63) == 0) { red[w][0] = s; red[w][1] = d; }
  __syncthreads();
  if (t == 0) {
    asn[2 * i]     = red[0][0] + red[1][0];   // head 0 = waves 0,1 (threads 0-127)
    asn[2 * i + 1] = red[2][0] + red[3][0];   // head 1 = waves 2,3
    adn[2 * i]     = red[0][1] + red[1][1];
    adn[2 * i + 1] = red[2][1] + red[3][1];
  }
}

// wave-per-node GAT aggregation with half-wave head specialization:
// lanes 0-31 handle head 0, lanes 32-63 head 1 — halves expf + asn loads.
__global__ __launch_bounds__(256) void gat_agg_w(
    const f16* __restrict__ h, const int* __restrict__ row_ptr,
    const int* __restrict__ csr_src, const float* __restrict__ asn,
    const float* __restrict__ adn, const float* __restrict__ bias,
    f16* __restrict__ out) {
  int node = blockIdx.x * 4 + (threadIdx.x >> 6);
  int l = threadIdx.x & 63;
  int hl = l & 31;                 // lane within half-wave
  int hd = (l >> 5) & 1;           // head id: 0 for lanes 0-31, 1 for lanes 32-63
  int beg = row_ptr[node], end = row_ptr[node + 1];
  float aD = adn[2 * node + hd];

  // pass 1: each half-wave covers ALL edges (stride 32) for its own head
  float m = -3.4e38f;
  for (int e = beg + hl; e < end; e += 32) {
    int s = csr_src[e];
    m = fmaxf(m, lrelu(asn[2 * s + hd] + aD));
  }
#pragma unroll
  for (int o = 16; o > 0; o >>= 1) m = fmaxf(m, __shfl_xor(m, o));
  float M = m;                     // uniform within half-wave

  // pass 2: serial edge walk — own-head weight only; sw accumulated in edge order
  const f16x8* h8 = (const f16x8*)h;
  float acc[8] = {};
  float sw = 0.f;
  int e = beg;
  for (; e + 4 <= end; e += 4) {
    int s0 = csr_src[e], s1 = csr_src[e + 1], s2 = csr_src[e + 2], s3 = csr_src[e + 3];
    float u0 = expf(lrelu(asn[2 * s0 + hd] + aD) - M);
    float u1 = expf(lrelu(asn[2 * s1 + hd] + aD) - M);
    float u2 = expf(lrelu(asn[2 * s2 + hd] + aD) - M);
    float u3 = expf(lrelu(asn[2 * s3 + hd] + aD) - M);
    sw += u0 + u1 + u2 + u3;
    f16x8 v0 = h8[(size_t)s0 * 64 + l];
    f16x8 v1 = h8[(size_t)s1 * 64 + l];
    f16x8 v2 = h8[(size_t)s2 * 64 + l];
    f16x8 v3 = h8[(size_t)s3 * 64 + l];
#pragma unroll
    for (int k = 0; k < 8; ++k)
      acc[k] += u0 * (float)v0[k] + u1 * (float)v1[k] + u2 * (float)v2[k] + u3 * (float)v3[k];
  }
  for (; e < end; ++e) {
    int s = csr_src[e];
    float u = expf(lrelu(asn[2 * s + hd] + aD) - M);
    sw += u;
    f16x8 v = h8[(size_t)s * 64 + l];
#pragma unroll
    for (int k = 0; k < 8; ++k) acc[k] += u * (float)v[k];
  }
  float iS = 1.f / sw;
  float4 b0 = ((const float4*)bias)[l * 2];
  float4 b1 = ((const float4*)bias)[l * 2 + 1];
  f16x8 o;
  o[0] = (f16)(acc[0] * iS + b0.x); o[1] = (f16)(acc[1] * iS + b0.y);
  o[2] = (f16)(acc[2] * iS + b0.z); o[3] = (f16)(acc[3] * iS + b0.w);
  o[4] = (f16)(acc[4] * iS + b1.x); o[5] = (f16)(acc[5] * iS + b1.y);
  o[6] = (f16)(acc[6] * iS + b1.z); o[7] = (f16)(acc[7] * iS + b1.w);
  ((f16x8*)out)[(size_t)node * 64 + l] = o;
}

// ---------------- pooling (fp16 input, f16x2-vectorized) ----------------

__global__ void graph_starts(const int* __restrict__ batch, int* __restrict__ start) {
  int i = blockIdx.x * blockDim.x + threadIdx.x;
  if (i >= N_NODES) return;
  int b = batch[i];
  int bp = (i == 0) ? -1 : batch[i - 1];
  for (int g = bp + 1; g <= b; ++g) start[g] = i;
  if (i == N_NODES - 1) {
    for (int g = b + 1; g <= NB; ++g) start[g] = N_NODES;
  }
}

// partial pool: grid (NB, POOL_SPLIT); thread t covers features 2t,2t+1
__global__ __launch_bounds__(256) void pool_part(const f16* __restrict__ h,
                                                 const int* __restrict__ start,
                                                 float* __restrict__ pp_sum,
                                                 float* __restrict__ pp_max) {
  int b = blockIdx.x, ch = blockIdx.y, t = threadIdx.x;
  int s = start[b], e = start[b + 1];
  int len = e - s;
  int c0 = s + (len * ch) / POOL_SPLIT;
  int c1 = s + (len * (ch + 1)) / POOL_SPLIT;
  const f16x2* h2 = (const f16x2*)h;
  float s0 = 0.f, s1 = 0.f, m0 = -3.4e38f, m1 = -3.4e38f;
  int r = c0;
  for (; r + 2 <= c1; r += 2) {
    f16x2 v0 = h2[(size_t)(r + 0) * 256 + t];
    f16x2 v1 = h2[(size_t)(r + 1) * 256 + t];
    float a0 = (float)v0.x, a1 = (float)v0.y, b0 = (float)v1.x, b1 = (float)v1.y;
    s0 += a0 + b0; s1 += a1 + b1;
    m0 = fmaxf(m0, fmaxf(a0, b0));
    m1 = fmaxf(m1, fmaxf(a1, b1));
  }
  for (; r < c1; ++r) {
    f16x2 v = h2[(size_t)r * 256 + t];
    float a0 = (float)v.x, a1 = (float)v.y;
    s0 += a0; s1 += a1;
    m0 = fmaxf(m0, a0); m1 = fmaxf(m1, a1);
  }
  size_t base = ((size_t)b * POOL_SPLIT + ch) * HID;
  pp_sum[base + 2 * t] = s0;
  pp_sum[base + 2 * t + 1] = s1;
  pp_max[base + 2 * t] = m0;
  pp_max[base + 2 * t + 1] = m1;
}

__global__ __launch_bounds__(512) void pool_comb(const float* __restrict__ pp_sum,
                                                 const float* __restrict__ pp_max,
                                                 const int* __restrict__ start,
                                                 float* __restrict__ p) {
  int b = blockIdx.x, t = threadIdx.x;
  float sum = 0.f, mx = -3.4e38f;
#pragma unroll
  for (int ch = 0; ch < POOL_SPLIT; ++ch) {
    sum += pp_sum[((size_t)b * POOL_SPLIT + ch) * HID + t];
    mx = fmaxf(mx, pp_max[((size_t)b * POOL_SPLIT + ch) * HID + t]);
  }
  float cnt = (float)(start[b + 1] - start[b]);
  p[b * 1024 + t] = sum / fmaxf(cnt, 1.f);
  p[b * 1024 + 512 + t] = mx;
}

// ---------------- classifier ----------------

__global__ __launch_bounds__(256) void fc_wave(const float* __restrict__ A,
                                               const float* __restrict__ WT,
                                               const float* __restrict__ bias,
                                               float* __restrict__ C, int K, int Ncol) {
  int r = blockIdx.x;
  int wid = threadIdx.x >> 6, l = threadIdx.x & 63;
  int c = blockIdx.y * 4 + wid;
  if (c >= Ncol) return;
  const float* a = A + (size_t)r * K;
  const float* w = WT + (size_t)c * K;
  float s = 0.f;
  for (int k = l; k < K; k += 64) s += a[k] * w[k];
#pragma unroll
  for (int o = 32; o > 0; o >>= 1) s += __shfl_down(s, o);
  if (l == 0) C[(size_t)r * Ncol + c] = s + bias[c];
}

__global__ void bn_small(float* __restrict__ X, int R, int C,
                         const float* __restrict__ g, const float* __restrict__ b, int act) {
  int c = blockIdx.x * blockDim.x + threadIdx.x;
  if (c >= C) return;
  float s = 0.f, q = 0.f;
  for (int r = 0; r < R; ++r) {
    float v = X[r * C + c];
    s += v; q += v * v;
  }
  float mu = s / R;
  float var = q / R - mu * mu;
  float sc = g[c] * rsqrtf(var + 1e-5f);
  float bb = b[c];
  for (int r = 0; r < R; ++r) {
    float v = sc * (X[r * C + c] - mu) + bb;
    if (act == 1) v = v > 0.f ? v : 0.2f * v;
    X[r * C + c] = v;
  }
}

// ---------------- launch ----------------

extern "C" void kernel_launch(void* const* d_in, const int* in_sizes, int n_in,
                              void* d_out, int out_size, void* d_ws, size_t ws_size,
                              hipStream_t stream) {
  const float* x      = (const float*)d_in[0];
  const int*   ei     = (const int*)d_in[1];
  const int*   batch  = (const int*)d_in[2];
  const float* ft_W   = (const float*)d_in[3];
  const float* ft_b   = (const float*)d_in[4];
  const float* ft_g   = (const float*)d_in[5];
  const float* ft_be  = (const float*)d_in[6];
  const float* gcn1_W = (const float*)d_in[7];
  const float* gcn1_b = (const float*)d_in[8];
  const float* gbn1_g = (const float*)d_in[9];
  const float* gbn1_b = (const float*)d_in[10];
  const float* gcn2_W = (const float*)d_in[11];
  const float* gcn2_b = (const float*)d_in[12];
  const float* gbn2_g = (const float*)d_in[13];
  const float* gbn2_b = (const float*)d_in[14];
  const float* gat1_W = (const float*)d_in[15];
  const float* gat1_as= (const float*)d_in[16];
  const float* gat1_ad= (const float*)d_in[17];
  const float* gat1_b = (const float*)d_in[18];
  const float* abn1_g = (const float*)d_in[19];
  const float* abn1_b = (const float*)d_in[20];
  const float* gat2_W = (const float*)d_in[21];
  const float* gat2_as= (const float*)d_in[22];
  const float* gat2_ad= (const float*)d_in[23];
  const float* gat2_b = (const float*)d_in[24];
  const float* abn2_g = (const float*)d_in[25];
  const float* abn2_b = (const float*)d_in[26];
  const float* fc1_W  = (const float*)d_in[27];
  const float* fc1_b  = (const float*)d_in[28];
  const float* cbn1_g = (const float*)d_in[29];
  const float* cbn1_b = (const float*)d_in[30];
  const float* fc2_W  = (const float*)d_in[31];
  const float* fc2_b  = (const float*)d_in[32];
  const float* cbn2_g = (const float*)d_in[33];
  const float* cbn2_b = (const float*)d_in[34];
  const float* out_W  = (const float*)d_in[35];
  const float* out_b  = (const float*)d_in[36];

  char* ws = (char*)d_ws;
  size_t off = 0;
  auto alloc = [&](size_t bytes) -> void* {
    void* p = ws + off;
    off = (off + bytes + 255) & ~(size_t)255;
    return p;
  };

  float* buf0 = (float*)alloc((size_t)M_PAD2 * HID * 4);       // fp16 X plane (aliases xhi/xlo early)
  float* buf1 = (float*)alloc((size_t)M_PAD2 * HID * 4);       // fp16 GEMM out
  unsigned short* ahi = (unsigned short*)alloc((size_t)M_PAD2 * HID * 2);
  unsigned short* alo = (unsigned short*)alloc((size_t)M_PAD2 * HID * 2);
  unsigned short* wh_ft = (unsigned short*)alloc((size_t)HID * F_IN * 2);
  unsigned short* wl_ft = (unsigned short*)alloc((size_t)HID * F_IN * 2);
  unsigned short* wh_g1 = (unsigned short*)alloc((size_t)HID * HID * 2);
  unsigned short* wl_g1 = (unsigned short*)alloc((size_t)HID * HID * 2);
  unsigned short* wh_g2 = (unsigned short*)alloc((size_t)HID * HID * 2);
  unsigned short* wl_g2 = (unsigned short*)alloc((size_t)HID * HID * 2);
  unsigned short* wh_a1 = (unsigned short*)alloc((size_t)HID * HID * 2);
  unsigned short* wl_a1 = (unsigned short*)alloc((size_t)HID * HID * 2);
  unsigned short* wh_a2 = (unsigned short*)alloc((size_t)HID * HID * 2);
  unsigned short* wl_a2 = (unsigned short*)alloc((size_t)HID * HID * 2);
  float* fc1t = (float*)alloc((size_t)512 * 1024 * 4);
  float* fc2t = (float*)alloc((size_t)256 * 512 * 4);
  float* outt = (float*)alloc((size_t)NCLS * 256 * 4);
  int*   row_ptr = (int*)alloc((N_NODES + 1) * 4);
  int*   cursor  = (int*)alloc(N_NODES * 4);
  int*   deg     = (int*)alloc(N_NODES * 4);
  int*   csr_src = (int*)alloc(EDG_ALL * 4);
  float* norm    = (float*)alloc(N_NODES * 4);
  float* asn     = (float*)alloc(N_NODES * 2 * 4);
  float* adn     = (float*)alloc(N_NODES * 2 * 4);
  float* stats   = (float*)alloc(1024 * 4);
  float* spart   = (float*)alloc((size_t)NPART * 1024 * 4);
  int*   bsum    = (int*)alloc(128 * 4);
  int*   boff    = (int*)alloc(128 * 4);
  int*   start   = (int*)alloc((NB + 1) * 4);
  float* p       = (float*)alloc(NB * 1024 * 4);
  float* pp_sum  = (float*)alloc((size_t)NB * POOL_SPLIT * HID * 4);
  float* pp_max  = (float*)alloc((size_t)NB * POOL_SPLIT * HID * 4);
  float* z1      = (float*)alloc(NB * HID * 4);
  float* z2      = (float*)alloc(NB * 256 * 4);
  // x hi/lo alias buf0 (dead before buf0 first written by gcn_agg)
  unsigned short* xhi = (unsigned short*)buf0;
  unsigned short* xlo = xhi + (size_t)M_PAD2 * F_IN;
  f16* xbuf = (f16*)buf0;   // fp16 X plane (agg outputs)
  f16* hbuf = (f16*)buf1;   // fp16 GEMM output view

  const dim3 blk256(256);
  const dim3 mmGrid(ROW_BLKS * 4);   // linear grid, XCD-swizzled inside kernel
  const int aggGrid = N_NODES / 4;   // wave-per-node, 4 nodes/block

  // BN macro: NPART-atomic colstats + combine (self-zeroing spart) + bn_act
#define BN_BLOCK(XBUF, G, B, ACT, WX)                                            \
  colstats<<<BN_GRID, blk256, 0, stream>>>(XBUF, N_NODES, spart);                \
  stats_comb<<<4, blk256, 0, stream>>>(spart, stats);                            \
  bn_act<<<BN_GRID, blk256, 0, stream>>>(XBUF, N_NODES, stats, G, B, ACT, ahi, alo, WX);

  // --- graph preprocessing ---
  hipMemsetAsync(deg, 0, N_NODES * 4, stream);
  hipMemsetAsync(spart, 0, (size_t)NPART * 1024 * 4, stream);   // once; stats_comb re-zeroes
  deg_count<<<(EDG_ALL + 255) / 256, blk256, 0, stream>>>(ei, deg);
  scan_p1<<<NBLK_SCAN, blk256, 0, stream>>>(deg, bsum);
  scan_p2<<<1, 128, 0, stream>>>(bsum, boff);
  scan_p3<<<NBLK_SCAN, blk256, 0, stream>>>(deg, boff, row_ptr);
  compute_norm<<<(N_NODES + 255) / 256, blk256, 0, stream>>>(deg, norm);
  hipMemcpyAsync(cursor, row_ptr, N_NODES * 4, hipMemcpyDeviceToDevice, stream);
  fill_csr<<<(EDG_ALL + 255) / 256, blk256, 0, stream>>>(ei, cursor, csr_src);

  // --- weight prep (split bf16, transposed) ---
  wtrans_split<<<dim3(HID / 32, F_IN / 32), blk256, 0, stream>>>(ft_W, wh_ft, wl_ft, F_IN, HID);
  wtrans_split<<<dim3(HID / 32, HID / 32), blk256, 0, stream>>>(gcn1_W, wh_g1, wl_g1, HID, HID);
  wtrans_split<<<dim3(HID / 32, HID / 32), blk256, 0, stream>>>(gcn2_W, wh_g2, wl_g2, HID, HID);
  wtrans_split<<<dim3(HID / 32, HID / 32), blk256, 0, stream>>>(gat1_W, wh_a1, wl_a1, HID, HID);
  wtrans_split<<<dim3(HID / 32, HID / 32), blk256, 0, stream>>>(gat2_W, wh_a2, wl_a2, HID, HID);
  ftrans<<<dim3(512 / 32, 1024 / 32), blk256, 0, stream>>>(fc1_W, fc1t, 1024, 512);
  ftrans<<<dim3(256 / 32, 512 / 32), blk256, 0, stream>>>(fc2_W, fc2t, 512, 256);
  ftrans<<<dim3((NCLS + 31) / 32, 256 / 32), blk256, 0, stream>>>(out_W, outt, 256, NCLS);

  // --- feature transform: Linear(split MFMA, fp16 out) -> BN -> LeakyReLU ---
  conv_split4<<<(N_NODES * F_IN / 4 + 255) / 256, blk256, 0, stream>>>(x, xhi, xlo, N_NODES * F_IN / 4);
  mm_split<F_IN, f16><<<mmGrid, blk256, 0, stream>>>(xhi, xlo, wh_ft, wl_ft, ft_b, hbuf);
  BN_BLOCK(hbuf, ft_g, ft_be, 1, 0)

  // --- GCN1 ---
  mm_split<HID, f16><<<mmGrid, blk256, 0, stream>>>(ahi, alo, wh_g1, wl_g1, nullptr, hbuf);
  gcn_agg_w<<<aggGrid, blk256, 0, stream>>>(hbuf, row_ptr, csr_src, norm, gcn1_b, xbuf);
  BN_BLOCK(xbuf, gbn1_g, gbn1_b, 2, 0)

  // --- GCN2 ---
  mm_split<HID, f16><<<mmGrid, blk256, 0, stream>>>(ahi, alo, wh_g2, wl_g2, nullptr, hbuf);
  gcn_agg_w<<<aggGrid, blk256, 0, stream>>>(hbuf, row_ptr, csr_src, norm, gcn2_b, xbuf);
  BN_BLOCK(xbuf, gbn2_g, gbn2_b, 2, 0)

  // --- GAT1 ---
  mm_split<HID, f16><<<mmGrid, blk256, 0, stream>>>(ahi, alo, wh_a1, wl_a1, nullptr, hbuf);
  gat_prep_h<<<N_NODES, blk256, 0, stream>>>(hbuf, gat1_as, gat1_ad, asn, adn);
  gat_agg_w<<<aggGrid, blk256, 0, stream>>>(hbuf, row_ptr, csr_src, asn, adn, gat1_b, xbuf);
  BN_BLOCK(xbuf, abn1_g, abn1_b, 2, 0)

  // --- GAT2 ---
  mm_split<HID, f16><<<mmGrid, blk256, 0, stream>>>(ahi, alo, wh_a2, wl_a2, nullptr, hbuf);
  gat_prep_h<<<N_NODES, blk256, 0, stream>>>(hbuf, gat2_as, gat2_ad, asn, adn);
  gat_agg_w<<<aggGrid, blk256, 0, stream>>>(hbuf, row_ptr, csr_src, asn, adn, gat2_b, xbuf);
  BN_BLOCK(xbuf, abn2_g, abn2_b, 2, 1)

  // --- pooling (reads fp16 X) ---
  graph_starts<<<(N_NODES + 255) / 256, blk256, 0, stream>>>(batch, start);
  pool_part<<<dim3(NB, POOL_SPLIT), blk256, 0, stream>>>(xbuf, start, pp_sum, pp_max);
  pool_comb<<<NB, dim3(512), 0, stream>>>(pp_sum, pp_max, start, p);

  // --- classifier ---
  fc_wave<<<dim3(NB, 128), blk256, 0, stream>>>(p, fc1t, fc1_b, z1, 1024, 512);
  bn_small<<<2, blk256, 0, stream>>>(z1, NB, 512, cbn1_g, cbn1_b, 0);
  fc_wave<<<dim3(NB, 64), blk256, 0, stream>>>(z1, fc2t, fc2_b, z2, 512, 256);
  bn_small<<<1, blk256, 0, stream>>>(z2, NB, 256, cbn2_g, cbn2_b, 1);
  fc_wave<<<dim3(NB, 10), blk256, 0, stream>>>(z2, outt, out_b, (float*)d_out, 256, NCLS);

#undef BN_BLOCK
  (void)in_sizes; (void)n_in; (void)out_size; (void)ws_size;
}